// Round 1
// baseline (3760.549 us; speedup 1.0000x reference)
//
#include <hip/hip_runtime.h>
#include <hip/hip_cooperative_groups.h>
#include <math.h>

namespace cg = cooperative_groups;

// Problem constants
#define Bb   64
#define Cc   100
#define Ff   2048
#define Tt   32
#define Hh   300
#define COMBc 2648
#define KP   2688   // COMB padded to 12*224 (224 = 14*16)
#define N4P  1280   // 4 gates * H padded to 20*64, interleaved n = 4*col + gate
#define KSG  12     // k-splits for gate GEMM
#define KLEN 224    // KP / KSG
#define KPP  2368   // 2048+300 padded to 148*16
#define NPP  336    // 300 padded to 7*48
#define KOP  304    // 300 padded to 19*16
#define NH   624    // 2*H padded to 13*48 (h0/c0 interleaved n = 2*col + g)
#define BOSi 1

__device__ __forceinline__ float sigmf_(float x){ return 1.0f/(1.0f + expf(-x)); }

__device__ __forceinline__ void fma16_(const float4 av, const float4 bv, float acc[4][4]){
    acc[0][0] += av.x*bv.x; acc[0][1] += av.x*bv.y; acc[0][2] += av.x*bv.z; acc[0][3] += av.x*bv.w;
    acc[1][0] += av.y*bv.x; acc[1][1] += av.y*bv.y; acc[1][2] += av.y*bv.z; acc[1][3] += av.y*bv.w;
    acc[2][0] += av.z*bv.x; acc[2][1] += av.z*bv.y; acc[2][2] += av.z*bv.z; acc[2][3] += av.z*bv.w;
    acc[3][0] += av.w*bv.x; acc[3][1] += av.w*bv.y; acc[3][2] += av.w*bv.z; acc[3][3] += av.w*bv.w;
}

// ---------------------------------------------------------------------------
// Pack weights:
//  W4p  (KP x N4P)  gate-interleaved n=4*col+g, padded cols zero
//  Wpp  ([Wcp;Whp] KPP x NPP)
//  Wopp (KOP x NPP)
//  Whc  ([Wh0|Wc0] Ff x NH) interleaved n=2*col+g
//  b4 (N4P), bp (NPP = bcp+bhp), bhc (NH interleaved bh0/bc0)
// ---------------------------------------------------------------------------
__global__ void k_pack(const float* Wi, const float* Wf, const float* Wo, const float* Wg,
                       const float* bi, const float* bf, const float* bo, const float* bg,
                       const float* Wcp, const float* Whp, const float* Wop,
                       const float* bcp, const float* bhp,
                       const float* Wh0, const float* Wc0, const float* bh0, const float* bc0,
                       float* W4p, float* Wpp, float* Wopp, float* Whc,
                       float* b4, float* bp, float* bhc)
{
    const int total = KP*N4P + KPP*NPP + KOP*NPP + Ff*NH + N4P + NPP + NH;
    for (int idx = blockIdx.x*256 + threadIdx.x; idx < total; idx += gridDim.x*256) {
        int i = idx;
        if (i < KP*N4P) {
            int j = i / N4P, n = i % N4P, c = n >> 2, g = n & 3;
            const float* W = (g==0)?Wi:(g==1)?Wf:(g==2)?Wo:Wg;
            W4p[i] = (j < COMBc && c < Hh) ? W[j*Hh + c] : 0.0f;
            continue;
        }
        i -= KP*N4P;
        if (i < KPP*NPP) {
            int j = i / NPP, n = i % NPP;
            float v = 0.0f;
            if (n < Hh) {
                if (j < Ff) v = Wcp[j*Hh + n];
                else if (j < Ff+Hh) v = Whp[(j-Ff)*Hh + n];
            }
            Wpp[i] = v;
            continue;
        }
        i -= KPP*NPP;
        if (i < KOP*NPP) {
            int j = i / NPP, n = i % NPP;
            Wopp[i] = (j < Hh && n < Hh) ? Wop[j*Hh + n] : 0.0f;
            continue;
        }
        i -= KOP*NPP;
        if (i < Ff*NH) {
            int j = i / NH, n = i % NH, c = n >> 1, g = n & 1;
            Whc[i] = (c < Hh) ? (g ? Wc0[j*Hh + c] : Wh0[j*Hh + c]) : 0.0f;
            continue;
        }
        i -= Ff*NH;
        if (i < N4P) {
            int c = i >> 2, g = i & 3;
            const float* bb = (g==0)?bi:(g==1)?bf:(g==2)?bo:bg;
            b4[i] = (c < Hh) ? bb[c] : 0.0f;
            continue;
        }
        i -= N4P;
        if (i < NPP) {
            bp[i] = (i < Hh) ? (bcp[i] + bhp[i]) : 0.0f;
            continue;
        }
        i -= NPP;
        { int c = i >> 1, g = i & 1;
          bhc[i] = (c < Hh) ? (g ? bc0[c] : bh0[c]) : 0.0f; }
    }
}

// ---------------------------------------------------------------------------
// meanT[f][b] = mean over channels. grid (8 f-tiles, 64 b), 256 thr.
// ---------------------------------------------------------------------------
__global__ __launch_bounds__(256) void k_meanT(const float* enc, float* meanT)
{
    const int b = blockIdx.y, f = blockIdx.x*256 + threadIdx.x;
    const float* pe = enc + (b*Cc)*Ff + f;
    float s = 0.0f;
#pragma unroll 10
    for (int c = 0; c < Cc; c++) s += pe[c*Ff];
    meanT[f*64 + b] = s * (1.0f/Cc);
}

// e_enc[b][c] = dot(enc[b,c,:], We_enc). grid (25 c-groups, 64 b), wave per c.
__global__ __launch_bounds__(256) void k_eenc(const float* enc, const float* We_enc, float* e_enc)
{
    const int b = blockIdx.y;
    const int w = threadIdx.x >> 6, lane = threadIdx.x & 63;
    const int c = blockIdx.x*4 + w;
    if (c < Cc) {
        const float* p = enc + (b*Cc + c)*Ff;
        float s = 0.0f;
        for (int k = lane; k < Ff; k += 64) s += p[k]*We_enc[k];
        for (int o = 32; o; o >>= 1) s += __shfl_xor(s, o);
        if (lane == 0) e_enc[b*Cc + c] = s;
    }
}

// Embedding gather E[t][j][b], coalesced reads of emb rows.
__global__ void k_embed(const int* caps, const float* emb, float* E)
{
    const int idx = blockIdx.x*256 + threadIdx.x;
    if (idx >= (Tt-1)*Hh*Bb) return;
    const int j = idx % Hh;
    const int bt = idx / Hh;
    const int b = bt / (Tt-1), t = bt % (Tt-1);
    E[(t*Hh + j)*64 + b] = emb[(long)caps[b*Tt + t]*Hh + j];
}

// out[:,0,:] = embedding[BOS]
__global__ void k_bos(const float* emb, float* out)
{
    const int idx = blockIdx.x*256 + threadIdx.x;
    if (idx >= Bb*Hh) return;
    const int b = idx / Hh, j = idx % Hh;
    out[(b*Tt)*Hh + j] = emb[(long)BOSi*Hh + j];
}

// ---------------------------------------------------------------------------
// h0/c0 GEMM: meanT (64 x 2048, k-major) @ Whc (2048 x 624). grid (13, 8 ksplit).
// ---------------------------------------------------------------------------
__global__ __launch_bounds__(192) void k_gemm_h0(const float* meanT, const float* Whc, float* parth)
{
    const int nt = blockIdx.x, ks = blockIdx.y, tid = threadIdx.x;
    const int n0 = nt*48, tx = tid % 12, ty = tid / 12;
    __shared__ float As[16][64];
    __shared__ float Bs[16][48];
    float acc[4][4] = {};
    const int k0 = ks*256;
    for (int kb = 0; kb < 16; kb++) {
        const int kbase = k0 + kb*16;
        for (int idx = tid; idx < 1024; idx += 192) {
            int kk = idx >> 6, bb = idx & 63;
            As[kk][bb] = meanT[(kbase + kk)*64 + bb];
        }
        for (int idx = tid; idx < 768; idx += 192) {
            int kk = idx / 48, nn = idx % 48;
            Bs[kk][nn] = Whc[(kbase + kk)*NH + n0 + nn];
        }
        __syncthreads();
#pragma unroll
        for (int kk = 0; kk < 16; kk++) {
            float4 av = *(const float4*)&As[kk][ty*4];
            float4 bv = *(const float4*)&Bs[kk][tx*4];
            fma16_(av, bv, acc);
        }
        __syncthreads();
    }
#pragma unroll
    for (int i = 0; i < 4; i++)
        *(float4*)&parth[(ks*64 + ty*4 + i)*NH + n0 + tx*4]
            = make_float4(acc[i][0], acc[i][1], acc[i][2], acc[i][3]);
}

// ---------------------------------------------------------------------------
// Shared epilogue: energy + softmax, h of current step in hbuf. Writes attnbuf[b][0..127].
// ---------------------------------------------------------------------------
__device__ __forceinline__ void attn_softmax(int b, const float* e_enc,
                                             const float* We_hid, float bev,
                                             const float* hbuf, float* red, float* attnbuf)
{
    const int tid = threadIdx.x;
    float p = hbuf[tid]*We_hid[tid];
    if (tid + 256 < Hh) p += hbuf[tid+256]*We_hid[tid+256];
    red[tid] = p;
    __syncthreads();
    for (int s = 128; s > 0; s >>= 1) {
        if (tid < s) red[tid] += red[tid + s];
        __syncthreads();
    }
    const float eh = red[0] + bev;
    if (tid < 64) {
        float v0 = e_enc[b*Cc + tid] + eh;
        float v1 = (tid + 64 < Cc) ? (e_enc[b*Cc + tid + 64] + eh) : -1e30f;
        float m = fmaxf(v0, v1);
        for (int o = 32; o; o >>= 1) m = fmaxf(m, __shfl_xor(m, o));
        float e0 = expf(v0 - m);
        float e1 = (tid + 64 < Cc) ? expf(v1 - m) : 0.0f;
        float s = e0 + e1;
        for (int o = 32; o; o >>= 1) s += __shfl_xor(s, o);
        float inv = 1.0f / s;
        attnbuf[b*128 + tid]      = e0 * inv;
        attnbuf[b*128 + tid + 64] = e1 * inv;
    }
}

// h0/c0 epilogue + attention for step 1 (attn_0 -> attnbuf).
__global__ __launch_bounds__(256) void k_h0fin(const float* parth, const float* bhc,
                                               const float* e_enc, const float* We_hid,
                                               const float* be,
                                               float* hT, float* cst, float* attnbuf)
{
    const int b = blockIdx.x, tid = threadIdx.x;
    __shared__ float hbuf[Hh];
    __shared__ float red[256];
    for (int col = tid; col < Hh; col += 256) {
        float sh = bhc[2*col], sc = bhc[2*col+1];
        for (int ks = 0; ks < 8; ks++) {
            const float2 v = *(const float2*)&parth[(ks*64 + b)*NH + 2*col];
            sh += v.x; sc += v.y;
        }
        float h = tanhf(sh);
        cst[b*Hh + col] = tanhf(sc);
        hT[(0*Hh + col)*64 + b] = h;
        hbuf[col] = h;
    }
    __syncthreads();
    attn_softmax(b, e_enc, We_hid, be[0], hbuf, red, attnbuf);
}

// ---------------------------------------------------------------------------
// MEGA: the full 31-step recurrence in ONE cooperative kernel.
// Grid = 256 WGs x 256 threads.
//  Phase B (WGs 0..239): gate partial GEMM, tile 64b x 64n, k-split 12.
//  Phase A' (all 256 WGs, wg -> (b = wg>>2, ft = wg&3)):
//    - redundantly reduce gate partials for b -> LSTM cell -> h_t (ft==0 writes hT/cst)
//    - redundant softmax -> attn_t in LDS
//    - ctx_{t+1} for this WG's 512-wide f slice
//  2 grid.sync() per step instead of 3 kernel launches.
// ---------------------------------------------------------------------------
__global__ __launch_bounds__(256) void k_mega(
    const float* enc, const float* e_enc, const float* We_hid, const float* be,
    const float* E, const float* W4p, const float* b4,
    float* hT, float* c0buf, float* c1buf, float* ctxT,
    const float* attn0, float* part)
{
    cg::grid_group grid = cg::this_grid();
    const int wg = blockIdx.x, tid = threadIdx.x;
    __shared__ float As[16][64];
    __shared__ float Bs[16][64];
    __shared__ float hbuf[Hh];
    __shared__ float red[256];
    __shared__ float sattn[Cc];

    // ---- Phase A0: ctx_1 from attn_0 ----
    {
        const int b = wg >> 2, ft = wg & 3;
        if (tid < Cc) sattn[tid] = attn0[b*128 + tid];
        __syncthreads();
        const float* pe = enc + (b*Cc)*Ff;
        for (int f = ft*512 + tid; f < ft*512 + 512; f += 256) {
            float acc = 0.0f;
#pragma unroll 10
            for (int c = 0; c < Cc; c++) acc += sattn[c]*pe[c*Ff + f];
            ctxT[(0*Ff + f)*64 + b] = acc;
        }
    }
    grid.sync();

    for (int t = 1; t < Tt; t++) {
        // ---- Phase B: gate partial GEMM for step t ----
        if (wg < 240) {
            const int nt = wg % 20, ks = wg / 20;
            const int n0 = nt*64, tx = tid & 15, ty = tid >> 4;
            float acc[4][4] = {};
            const int k0 = ks*KLEN;
            const float* Esrc = E    + (t-1)*Hh*64;
            const float* hsrc = hT   + (t-1)*Hh*64;
            const float* csrc = ctxT + (t-1)*Ff*64;
            for (int kb = 0; kb < 14; kb++) {
                const int kbase = k0 + kb*16;
#pragma unroll
                for (int i = 0; i < 4; i++) {
                    int idx = tid + i*256;
                    int kk = idx >> 6, bb = idx & 63, j = kbase + kk;
                    float v;
                    if (j < Hh)           v = Esrc[j*64 + bb];
                    else if (j < 2*Hh)    v = hsrc[(j - Hh)*64 + bb];
                    else if (j < COMBc)   v = csrc[(j - 2*Hh)*64 + bb];
                    else                  v = 0.0f;
                    As[kk][bb] = v;
                }
#pragma unroll
                for (int i = 0; i < 4; i++) {
                    int idx = tid + i*256;
                    int kk = idx >> 6, nn = idx & 63;
                    Bs[kk][nn] = W4p[(kbase + kk)*N4P + n0 + nn];
                }
                __syncthreads();
#pragma unroll
                for (int kk = 0; kk < 16; kk++) {
                    float4 av = *(const float4*)&As[kk][ty*4];
                    float4 bv = *(const float4*)&Bs[kk][tx*4];
                    fma16_(av, bv, acc);
                }
                __syncthreads();
            }
#pragma unroll
            for (int i = 0; i < 4; i++)
                *(float4*)&part[(ks*64 + ty*4 + i)*N4P + n0 + tx*4]
                    = make_float4(acc[i][0], acc[i][1], acc[i][2], acc[i][3]);
        }
        grid.sync();

        // ---- Phase A': gates -> h_t -> attn_t -> ctx_{t+1} ----
        {
            const int b = wg >> 2, ft = wg & 3;
            const float* cold = (t & 1) ? c0buf : c1buf;
            float*       cnew = (t & 1) ? c1buf : c0buf;
            for (int col = tid; col < Hh; col += 256) {
                float4 s = ((const float4*)b4)[col];
                for (int ks = 0; ks < KSG; ks++) {
                    const float4 v = ((const float4*)part)[(ks*64 + b)*(N4P/4) + col];
                    s.x += v.x; s.y += v.y; s.z += v.z; s.w += v.w;
                }
                float ig = sigmf_(s.x), fg = sigmf_(s.y), og = sigmf_(s.z), gg = tanhf(s.w);
                float cn = fg*cold[b*Hh + col] + ig*gg;
                float h = og*tanhf(cn);
                hbuf[col] = h;
                if (ft == 0) {
                    cnew[b*Hh + col] = cn;
                    hT[(t*Hh + col)*64 + b] = h;
                }
            }
            __syncthreads();
            // softmax -> sattn (redundant per ft, all identical)
            float p = hbuf[tid]*We_hid[tid];
            if (tid + 256 < Hh) p += hbuf[tid+256]*We_hid[tid+256];
            red[tid] = p;
            __syncthreads();
            for (int s = 128; s > 0; s >>= 1) {
                if (tid < s) red[tid] += red[tid + s];
                __syncthreads();
            }
            const float eh = red[0] + be[0];
            if (tid < 64) {
                float v0 = e_enc[b*Cc + tid] + eh;
                float v1 = (tid + 64 < Cc) ? (e_enc[b*Cc + tid + 64] + eh) : -1e30f;
                float m = fmaxf(v0, v1);
                for (int o = 32; o; o >>= 1) m = fmaxf(m, __shfl_xor(m, o));
                float e0 = expf(v0 - m);
                float e1 = (tid + 64 < Cc) ? expf(v1 - m) : 0.0f;
                float ss = e0 + e1;
                for (int o = 32; o; o >>= 1) ss += __shfl_xor(ss, o);
                float inv = 1.0f / ss;
                sattn[tid] = e0 * inv;
                if (tid + 64 < Cc) sattn[tid + 64] = e1 * inv;
            }
            __syncthreads();
            if (t < Tt-1) {
                const float* pe = enc + (b*Cc)*Ff;
                for (int f = ft*512 + tid; f < ft*512 + 512; f += 256) {
                    float acc = 0.0f;
#pragma unroll 10
                    for (int c = 0; c < Cc; c++) acc += sattn[c]*pe[c*Ff + f];
                    ctxT[(t*Ff + f)*64 + b] = acc;
                }
            }
        }
        if (t < Tt-1) grid.sync();
    }
}

// ---------------------------------------------------------------------------
// Deferred prediction stage A: [ctx_t | h_t] @ [Wcp;Whp], batched over all t.
// ---------------------------------------------------------------------------
__global__ __launch_bounds__(192) void k_preda(const float* ctxT, const float* hT,
                                               const float* Wpp, float* ppart)
{
    const int nt = blockIdx.x, ti = blockIdx.y, ks = blockIdx.z, tid = threadIdx.x;
    const int n0 = nt*48, tx = tid % 12, ty = tid / 12;
    __shared__ float As[16][64];
    __shared__ float Bs[16][48];
    float acc[4][4] = {};
    const int k0 = ks*592;
    const float* csrc = ctxT + ti*Ff*64;
    const float* hsrc = hT + (ti+1)*Hh*64;

    for (int kb = 0; kb < 37; kb++) {
        const int kbase = k0 + kb*16;
        for (int idx = tid; idx < 1024; idx += 192) {
            int kk = idx >> 6, bb = idx & 63, j = kbase + kk;
            float v;
            if (j < Ff)          v = csrc[j*64 + bb];
            else if (j < Ff+Hh)  v = hsrc[(j - Ff)*64 + bb];
            else                 v = 0.0f;
            As[kk][bb] = v;
        }
        for (int idx = tid; idx < 768; idx += 192) {
            int kk = idx / 48, nn = idx % 48;
            Bs[kk][nn] = Wpp[(kbase + kk)*NPP + n0 + nn];
        }
        __syncthreads();
#pragma unroll
        for (int kk = 0; kk < 16; kk++) {
            float4 av = *(const float4*)&As[kk][ty*4];
            float4 bv = *(const float4*)&Bs[kk][tx*4];
            fma16_(av, bv, acc);
        }
        __syncthreads();
    }
#pragma unroll
    for (int jn = 0; jn < 4; jn++) {
        float4 v = make_float4(acc[0][jn], acc[1][jn], acc[2][jn], acc[3][jn]);
        *(float4*)&ppart[((ks*31 + ti)*NPP + n0 + tx*4 + jn)*64 + ty*4] = v;
    }
}

// Stage A2: reduce ksplit + add emb_prev + (bcp+bhp) -> tmpT[t][j(304)][b]
__global__ void k_preda2(const float* ppart, const float* E, const float* bp, float* tmpT)
{
    const int idx = blockIdx.x*256 + threadIdx.x;
    if (idx >= 31*KOP*64) return;
    const int ti = idx / (KOP*64);
    const int r = idx % (KOP*64);
    const int j = r / 64, b = r % 64;
    float v = 0.0f;
    if (j < Hh) {
        v = E[(ti*Hh + j)*64 + b] + bp[j];
        for (int ks = 0; ks < 4; ks++)
            v += ppart[((ks*31 + ti)*NPP + j)*64 + b];
    }
    tmpT[idx] = v;
}

// Stage B: out[:, t, :] = tmp @ Wop + bop. grid (7 ntiles, 31 t).
__global__ __launch_bounds__(192) void k_predb(const float* tmpT, const float* Wopp,
                                               const float* bop, float* out)
{
    const int nt = blockIdx.x, ti = blockIdx.y, tid = threadIdx.x;
    const int n0 = nt*48, tx = tid % 12, ty = tid / 12;
    __shared__ float As[16][64];
    __shared__ float Bs[16][48];
    float acc[4][4] = {};
    const float* Asrc = tmpT + ti*KOP*64;

    for (int kb = 0; kb < 19; kb++) {
        const int kbase = kb*16;
        for (int idx = tid; idx < 1024; idx += 192) {
            int kk = idx >> 6, bb = idx & 63;
            As[kk][bb] = Asrc[(kbase + kk)*64 + bb];
        }
        for (int idx = tid; idx < 768; idx += 192) {
            int kk = idx / 48, nn = idx % 48;
            Bs[kk][nn] = Wopp[(kbase + kk)*NPP + n0 + nn];
        }
        __syncthreads();
#pragma unroll
        for (int kk = 0; kk < 16; kk++) {
            float4 av = *(const float4*)&As[kk][ty*4];
            float4 bv = *(const float4*)&Bs[kk][tx*4];
            fma16_(av, bv, acc);
        }
        __syncthreads();
    }
#pragma unroll
    for (int i = 0; i < 4; i++) {
        const int bb = ty*4 + i;
#pragma unroll
        for (int j = 0; j < 4; j++) {
            const int n = n0 + tx*4 + j;
            if (n < Hh)
                out[(bb*Tt + (ti+1))*Hh + n] = acc[i][j] + bop[n];
        }
    }
}

// ---------------------------------------------------------------------------
extern "C" void kernel_launch(void* const* d_in, const int* in_sizes, int n_in,
                              void* d_out, int out_size, void* d_ws, size_t ws_size,
                              hipStream_t stream)
{
    const float* enc    = (const float*)d_in[0];
    const int*   caps   = (const int*)  d_in[1];
    const float* emb    = (const float*)d_in[2];
    const float* Wh0    = (const float*)d_in[3];
    const float* bh0    = (const float*)d_in[4];
    const float* Wc0    = (const float*)d_in[5];
    const float* bc0    = (const float*)d_in[6];
    const float* We_enc = (const float*)d_in[7];
    const float* We_hid = (const float*)d_in[8];
    const float* be     = (const float*)d_in[9];
    const float* Wi     = (const float*)d_in[10];
    const float* bi     = (const float*)d_in[11];
    const float* Wf     = (const float*)d_in[12];
    const float* bf     = (const float*)d_in[13];
    const float* Wo     = (const float*)d_in[14];
    const float* bo     = (const float*)d_in[15];
    const float* Wg     = (const float*)d_in[16];
    const float* bg     = (const float*)d_in[17];
    const float* Wcp    = (const float*)d_in[18];
    const float* bcp    = (const float*)d_in[19];
    const float* Whp    = (const float*)d_in[20];
    const float* bhp    = (const float*)d_in[21];
    const float* Wop    = (const float*)d_in[22];
    const float* bop    = (const float*)d_in[23];
    float* out = (float*)d_out;

    // Workspace carve-up (floats).
    float* w = (float*)d_ws;
    float* W4p     = w; w += KP*N4P;       // 3,440,640
    float* Wpp     = w; w += KPP*NPP;      //   795,648
    float* Wopp    = w; w += KOP*NPP;      //   102,144
    float* b4      = w; w += N4P;
    float* bp      = w; w += NPP;
    float* bhc     = w; w += NH;
    float* e_enc   = w; w += Bb*Cc;
    float* hT      = w; w += Tt*Hh*64;     // h_t, t=0..31, [t][col][b]
    float* ctxT    = w; w += 31*Ff*64;     // ctx_t, t=1..31, [t-1][f][b]
    float* E       = w; w += 31*Hh*64;     // emb_prev, [t][j][b]
    float* cst     = w; w += Bb*Hh;        // cell state ping
    float* cst2    = w; w += Bb*Hh;        // cell state pong
    float* attnbuf = w; w += 64*128;       // attn_0 only, [b][c]
    float* ppart   = w; w += 4*31*NPP*64;  // 2,666,496
    float* tmpT    = w; w += 31*KOP*64;    //   603,136
    // time-disjoint aliases:
    //  Whc  (k_pack->k_gemm_h0, 1,277,952) and part (k_mega, 983,040) both live
    //  only before/within phases that never overlap ppart's real use (k_preda+).
    float* Whc   = ppart;
    float* part  = ppart;                  // 12*64*1280 = 983,040 <= 2,666,496
    float* meanT = tmpT;                   // 2048*64 = 131,072
    float* parth = tmpT + 131072;          // 8*64*624 = 319,488 (fits 603,136)
    (void)ws_size; (void)in_sizes; (void)n_in; (void)out_size;

    k_pack<<<4096, 256, 0, stream>>>(Wi, Wf, Wo, Wg, bi, bf, bo, bg,
                                     Wcp, Whp, Wop, bcp, bhp,
                                     Wh0, Wc0, bh0, bc0,
                                     W4p, Wpp, Wopp, Whc, b4, bp, bhc);
    k_meanT<<<dim3(8, 64), 256, 0, stream>>>(enc, meanT);
    k_eenc <<<dim3(25, 64), 256, 0, stream>>>(enc, We_enc, e_enc);
    k_embed<<<2325, 256, 0, stream>>>(caps, emb, E);
    k_bos  <<<75, 256, 0, stream>>>(emb, out);
    k_gemm_h0<<<dim3(13, 8), 192, 0, stream>>>(meanT, Whc, parth);
    k_h0fin<<<64, 256, 0, stream>>>(parth, bhc, e_enc, We_hid, be, hT, cst, attnbuf);

    // One cooperative kernel replaces the 93-launch recurrence.
    {
        void* margs[] = {
            (void*)&enc, (void*)&e_enc, (void*)&We_hid, (void*)&be,
            (void*)&E, (void*)&W4p, (void*)&b4,
            (void*)&hT, (void*)&cst, (void*)&cst2, (void*)&ctxT,
            (void*)&attnbuf, (void*)&part
        };
        hipLaunchCooperativeKernel((const void*)k_mega, dim3(256), dim3(256),
                                   margs, 0, stream);
    }

    k_preda<<<dim3(7, 31, 4), 192, 0, stream>>>(ctxT, hT, Wpp, ppart);
    k_preda2<<<2356, 256, 0, stream>>>(ppart, E, bp, tmpT);
    k_predb<<<dim3(7, 31), 192, 0, stream>>>(tmpT, Wopp, bop, out);
}

// Round 2
// 2283.240 us; speedup vs baseline: 1.6470x; 1.6470x over previous
//
#include <hip/hip_runtime.h>
#include <hip/hip_cooperative_groups.h>
#include <math.h>

namespace cg = cooperative_groups;

// Problem constants
#define Bb   64
#define Cc   100
#define Ff   2048
#define Tt   32
#define Hh   300
#define N4P  1216   // 4 gates * H padded to 19*64, interleaved n = 4*col + gate
#define KH   304    // H padded to 19*16 (k dim of recurrent GEMM)
#define NPP  336    // 300 padded to 7*48
#define KOP  304    // 300 padded to 19*16
#define NH   624    // 2*H padded to 13*48 (h0/c0 interleaved n = 2*col + g)
#define BOSi 1

__device__ __forceinline__ float sigmf_(float x){ return 1.0f/(1.0f + expf(-x)); }

__device__ __forceinline__ void fma16_(const float4 av, const float4 bv, float acc[4][4]){
    acc[0][0] += av.x*bv.x; acc[0][1] += av.x*bv.y; acc[0][2] += av.x*bv.z; acc[0][3] += av.x*bv.w;
    acc[1][0] += av.y*bv.x; acc[1][1] += av.y*bv.y; acc[1][2] += av.y*bv.z; acc[1][3] += av.y*bv.w;
    acc[2][0] += av.z*bv.x; acc[2][1] += av.z*bv.y; acc[2][2] += av.z*bv.z; acc[2][3] += av.z*bv.w;
    acc[3][0] += av.w*bv.x; acc[3][1] += av.w*bv.y; acc[3][2] += av.w*bv.z; acc[3][3] += av.w*bv.w;
}

// ---------------------------------------------------------------------------
// Pack (small): W4h_p [KH][N4P] (h-rows of the gate weights, gate-interleaved
// n=4*col+g), b4p[N4P], pb_b[NPP]=bcp+bhp, bhc[NH] (bh0/bc0 interleaved).
// ---------------------------------------------------------------------------
__global__ void k_pack(const float* Wi, const float* Wf, const float* Wo, const float* Wg,
                       const float* bi, const float* bf, const float* bo, const float* bg,
                       const float* bcp, const float* bhp,
                       const float* bh0, const float* bc0,
                       float* W4h_p, float* b4p, float* pb_b, float* bhc)
{
    const int total = KH*N4P + N4P + NPP + NH;
    for (int idx = blockIdx.x*256 + threadIdx.x; idx < total; idx += gridDim.x*256) {
        int i = idx;
        if (i < KH*N4P) {
            int k = i / N4P, n = i % N4P, c = n >> 2, g = n & 3;
            const float* W = (g==0)?Wi:(g==1)?Wf:(g==2)?Wo:Wg;
            // h-block rows of comb are rows Hh..2*Hh-1
            W4h_p[i] = (k < Hh && c < Hh) ? W[(Hh + k)*Hh + c] : 0.0f;
            continue;
        }
        i -= KH*N4P;
        if (i < N4P) {
            int c = i >> 2, g = i & 3;
            const float* bb = (g==0)?bi:(g==1)?bf:(g==2)?bo:bg;
            b4p[i] = (c < Hh) ? bb[c] : 0.0f;
            continue;
        }
        i -= N4P;
        if (i < NPP) {
            pb_b[i] = (i < Hh) ? (bcp[i] + bhp[i]) : 0.0f;
            continue;
        }
        i -= NPP;
        { int c = i >> 1, g = i & 1;
          bhc[i] = (c < Hh) ? (g ? bc0[c] : bh0[c]) : 0.0f; }
    }
}

// ---------------------------------------------------------------------------
// meanT[f][b] = mean over channels. grid (8 f-tiles, 64 b), 256 thr.
// ---------------------------------------------------------------------------
__global__ __launch_bounds__(256) void k_meanT(const float* enc, float* meanT)
{
    const int b = blockIdx.y, f = blockIdx.x*256 + threadIdx.x;
    const float* pe = enc + (b*Cc)*Ff + f;
    float s = 0.0f;
#pragma unroll 10
    for (int c = 0; c < Cc; c++) s += pe[c*Ff];
    meanT[f*64 + b] = s * (1.0f/Cc);
}

// e_enc[b][c] = dot(enc[b,c,:], We_enc). grid (25 c-groups, 64 b), wave per c.
__global__ __launch_bounds__(256) void k_eenc(const float* enc, const float* We_enc, float* e_enc)
{
    const int b = blockIdx.y;
    const int w = threadIdx.x >> 6, lane = threadIdx.x & 63;
    const int c = blockIdx.x*4 + w;
    if (c < Cc) {
        const float* p = enc + (b*Cc + c)*Ff;
        float s = 0.0f;
        for (int k = lane; k < Ff; k += 64) s += p[k]*We_enc[k];
        for (int o = 32; o; o >>= 1) s += __shfl_xor(s, o);
        if (lane == 0) e_enc[b*Cc + c] = s;
    }
}

// attn[b][c] = softmax(e_enc[b,:]) -- the h term is constant over c, so the
// softmax is time-invariant. grid 64 blocks x 64 threads.
__global__ void k_attn(const float* e_enc, float* attnW)
{
    const int b = blockIdx.x, lane = threadIdx.x;
    float v0 = e_enc[b*Cc + lane];
    float v1 = (lane + 64 < Cc) ? e_enc[b*Cc + lane + 64] : -1e30f;
    float m = fmaxf(v0, v1);
    for (int o = 32; o; o >>= 1) m = fmaxf(m, __shfl_xor(m, o));
    float e0 = expf(v0 - m);
    float e1 = (lane + 64 < Cc) ? expf(v1 - m) : 0.0f;
    float s = e0 + e1;
    for (int o = 32; o; o >>= 1) s += __shfl_xor(s, o);
    float inv = 1.0f / s;
    attnW[b*Cc + lane] = e0 * inv;
    if (lane + 64 < Cc) attnW[b*Cc + lane + 64] = e1 * inv;
}

// ctx[f][b] = sum_c attn[b][c]*enc[b][c][f] -- ONCE. grid (8 f-tiles, 64 b).
__global__ __launch_bounds__(256) void k_ctx(const float* enc, const float* attnW, float* ctxT)
{
    const int b = blockIdx.y, f = blockIdx.x*256 + threadIdx.x;
    __shared__ float sA[128];
    if (threadIdx.x < Cc) sA[threadIdx.x] = attnW[b*Cc + threadIdx.x];
    __syncthreads();
    const float* pe = enc + (b*Cc)*Ff + f;
    float acc = 0.0f;
#pragma unroll 10
    for (int c = 0; c < Cc; c++) acc += sA[c] * pe[c*Ff];
    ctxT[f*64 + b] = acc;
}

// Embedding gather E[t][j][b], coalesced reads of emb rows.
__global__ void k_embed(const int* caps, const float* emb, float* E)
{
    const int idx = blockIdx.x*256 + threadIdx.x;
    if (idx >= (Tt-1)*Hh*Bb) return;
    const int j = idx % Hh;
    const int bt = idx / Hh;
    const int b = bt / (Tt-1), t = bt % (Tt-1);
    E[(t*Hh + j)*64 + b] = emb[(long)caps[b*Tt + t]*Hh + j];
}

// out[:,0,:] = embedding[BOS]
__global__ void k_bos(const float* emb, float* out)
{
    const int idx = blockIdx.x*256 + threadIdx.x;
    if (idx >= Bb*Hh) return;
    const int b = idx / Hh, j = idx % Hh;
    out[(b*Tt)*Hh + j] = emb[(long)BOSi*Hh + j];
}

// ---------------------------------------------------------------------------
// h0/c0 GEMM: meanT (64 x 2048, k-major) @ [Wh0|Wc0] (2048 x 624 interleaved,
// read raw). grid (13, 8 ksplit), 192 thr.
// ---------------------------------------------------------------------------
__global__ __launch_bounds__(192) void k_gemm_h0(const float* meanT,
                                                 const float* Wh0, const float* Wc0,
                                                 float* parth)
{
    const int nt = blockIdx.x, ks = blockIdx.y, tid = threadIdx.x;
    const int n0 = nt*48, tx = tid % 12, ty = tid / 12;
    __shared__ float As[16][64];
    __shared__ float Bs[16][48];
    float acc[4][4] = {};
    const int k0 = ks*256;
    for (int kb = 0; kb < 16; kb++) {
        const int kbase = k0 + kb*16;
        for (int idx = tid; idx < 1024; idx += 192) {
            int kk = idx >> 6, bb = idx & 63;
            As[kk][bb] = meanT[(kbase + kk)*64 + bb];
        }
        for (int idx = tid; idx < 768; idx += 192) {
            int kk = idx / 48, nn = idx % 48;
            int n = n0 + nn, col = n >> 1;
            const float* W = (n & 1) ? Wc0 : Wh0;
            Bs[kk][nn] = (col < Hh) ? W[(kbase + kk)*Hh + col] : 0.0f;
        }
        __syncthreads();
#pragma unroll
        for (int kk = 0; kk < 16; kk++) {
            float4 av = *(const float4*)&As[kk][ty*4];
            float4 bv = *(const float4*)&Bs[kk][tx*4];
            fma16_(av, bv, acc);
        }
        __syncthreads();
    }
#pragma unroll
    for (int i = 0; i < 4; i++)
        *(float4*)&parth[(ks*64 + ty*4 + i)*NH + n0 + tx*4]
            = make_float4(acc[i][0], acc[i][1], acc[i][2], acc[i][3]);
}

// h0/c0 epilogue: hT[0][col][b] = tanh, c0T[col][b] = tanh. grid 64 (b), 256 thr.
__global__ __launch_bounds__(256) void k_h0fin2(const float* parth, const float* bhc,
                                                float* hT, float* c0T)
{
    const int b = blockIdx.x, tid = threadIdx.x;
    for (int col = tid; col < Hh; col += 256) {
        float sh = bhc[2*col], sc = bhc[2*col+1];
        for (int ks = 0; ks < 8; ks++) {
            const float2 v = *(const float2*)&parth[(ks*64 + b)*NH + 2*col];
            sh += v.x; sc += v.y;
        }
        hT[(0*Hh + col)*64 + b] = tanhf(sh);
        c0T[col*64 + b] = tanhf(sc);
    }
}

// ---------------------------------------------------------------------------
// C partials: ctx (64 x 2048 k-major) @ W4c (2048 x 1216, gate-interleaved,
// read raw from Wi..Wg rows 600..2647). grid (19 nt, 8 ks), 256 thr, 64x64 tile.
// Output partC[ks][n][b].
// ---------------------------------------------------------------------------
__global__ __launch_bounds__(256) void k_gemm_C(const float* ctxT,
                                                const float* Wi, const float* Wf,
                                                const float* Wo, const float* Wg,
                                                float* partC)
{
    const int nt = blockIdx.x, ks = blockIdx.y, tid = threadIdx.x;
    const int n0 = nt*64, tx = tid & 15, ty = tid >> 4;
    __shared__ float As[16][64];
    __shared__ float Bs[16][64];
    float acc[4][4] = {};
    const int k0 = ks*256;
    for (int kb = 0; kb < 16; kb++) {
        const int kbase = k0 + kb*16;
#pragma unroll
        for (int i = 0; i < 4; i++) {
            int idx = tid + i*256;
            int kk = idx >> 6, bb = idx & 63;
            As[kk][bb] = ctxT[(kbase + kk)*64 + bb];
        }
#pragma unroll
        for (int i = 0; i < 4; i++) {
            int idx = tid + i*256;
            int kk = idx >> 6, nn = idx & 63;
            int n = n0 + nn, c = n >> 2, g = n & 3;
            const float* W = (g==0)?Wi:(g==1)?Wf:(g==2)?Wo:Wg;
            Bs[kk][nn] = (c < Hh) ? W[(2*Hh + kbase + kk)*Hh + c] : 0.0f;
        }
        __syncthreads();
#pragma unroll
        for (int kk = 0; kk < 16; kk++) {
            float4 av = *(const float4*)&As[kk][ty*4];
            float4 bv = *(const float4*)&Bs[kk][tx*4];
            fma16_(av, bv, acc);
        }
        __syncthreads();
    }
#pragma unroll
    for (int jn = 0; jn < 4; jn++) {
        float4 v = make_float4(acc[0][jn], acc[1][jn], acc[2][jn], acc[3][jn]);
        *(float4*)&partC[((ks*N4P) + n0 + tx*4 + jn)*64 + ty*4] = v;
    }
}

// ---------------------------------------------------------------------------
// gpre[t][n][b] = (E_t @ W4e)[n][b] + sum_ks partC + b4p[n].
// grid (19 nt, 31 t), 256 thr, 64x64 tile, K=304 single pass.
// ---------------------------------------------------------------------------
__global__ __launch_bounds__(256) void k_gemm_gpre(const float* E,
                                                   const float* Wi, const float* Wf,
                                                   const float* Wo, const float* Wg,
                                                   const float* partC, const float* b4p,
                                                   float* gpre)
{
    const int nt = blockIdx.x, t = blockIdx.y, tid = threadIdx.x;
    const int n0 = nt*64, tx = tid & 15, ty = tid >> 4;
    __shared__ float As[16][64];
    __shared__ float Bs[16][64];
    float acc[4][4] = {};
    for (int kb = 0; kb < 19; kb++) {
        const int kbase = kb*16;
#pragma unroll
        for (int i = 0; i < 4; i++) {
            int idx = tid + i*256;
            int kk = idx >> 6, bb = idx & 63, j = kbase + kk;
            As[kk][bb] = (j < Hh) ? E[(t*Hh + j)*64 + bb] : 0.0f;
        }
#pragma unroll
        for (int i = 0; i < 4; i++) {
            int idx = tid + i*256;
            int kk = idx >> 6, nn = idx & 63, j = kbase + kk;
            int n = n0 + nn, c = n >> 2, g = n & 3;
            const float* W = (g==0)?Wi:(g==1)?Wf:(g==2)?Wo:Wg;
            Bs[kk][nn] = (j < Hh && c < Hh) ? W[j*Hh + c] : 0.0f;
        }
        __syncthreads();
#pragma unroll
        for (int kk = 0; kk < 16; kk++) {
            float4 av = *(const float4*)&As[kk][ty*4];
            float4 bv = *(const float4*)&Bs[kk][tx*4];
            fma16_(av, bv, acc);
        }
        __syncthreads();
    }
#pragma unroll
    for (int jn = 0; jn < 4; jn++) {
        const int n = n0 + tx*4 + jn;
        float4 ps = make_float4(0,0,0,0);
        for (int ks = 0; ks < 8; ks++) {
            const float4 v = *(const float4*)&partC[(ks*N4P + n)*64 + ty*4];
            ps.x += v.x; ps.y += v.y; ps.z += v.z; ps.w += v.w;
        }
        const float bv = b4p[n];
        float4 o;
        o.x = acc[0][jn] + ps.x + bv;
        o.y = acc[1][jn] + ps.y + bv;
        o.z = acc[2][jn] + ps.z + bv;
        o.w = acc[3][jn] + ps.w + bv;
        *(float4*)&gpre[((t*N4P) + n)*64 + ty*4] = o;
    }
}

// ---------------------------------------------------------------------------
// pbias partials: ctx @ Wcp (2048 x 300, raw). grid (7 nt, 8 ks), 192 thr.
// Output ppb[ks][n(336)][b].
// ---------------------------------------------------------------------------
__global__ __launch_bounds__(192) void k_gemm_pb(const float* ctxT, const float* Wcp,
                                                 float* ppb)
{
    const int nt = blockIdx.x, ks = blockIdx.y, tid = threadIdx.x;
    const int n0 = nt*48, tx = tid % 12, ty = tid / 12;
    __shared__ float As[16][64];
    __shared__ float Bs[16][48];
    float acc[4][4] = {};
    const int k0 = ks*256;
    for (int kb = 0; kb < 16; kb++) {
        const int kbase = k0 + kb*16;
        for (int idx = tid; idx < 1024; idx += 192) {
            int kk = idx >> 6, bb = idx & 63;
            As[kk][bb] = ctxT[(kbase + kk)*64 + bb];
        }
        for (int idx = tid; idx < 768; idx += 192) {
            int kk = idx / 48, nn = idx % 48, n = n0 + nn;
            Bs[kk][nn] = (n < Hh) ? Wcp[(kbase + kk)*Hh + n] : 0.0f;
        }
        __syncthreads();
#pragma unroll
        for (int kk = 0; kk < 16; kk++) {
            float4 av = *(const float4*)&As[kk][ty*4];
            float4 bv = *(const float4*)&Bs[kk][tx*4];
            fma16_(av, bv, acc);
        }
        __syncthreads();
    }
#pragma unroll
    for (int jn = 0; jn < 4; jn++) {
        float4 v = make_float4(acc[0][jn], acc[1][jn], acc[2][jn], acc[3][jn]);
        *(float4*)&ppb[((ks*NPP) + n0 + tx*4 + jn)*64 + ty*4] = v;
    }
}

// ---------------------------------------------------------------------------
// Recurrence: 31 steps, one grid.sync per step. 19 WGs x 1024 threads.
// Thread owns (b = tid&63, hcol = nt*16 + tid>>6); cell state in register.
// gates = h_{t-1} @ W4h_p + gpre[t-1]; h_t written to hT[t].
// ---------------------------------------------------------------------------
__global__ __launch_bounds__(1024) void k_rec(const float* W4h_p, const float* gpre,
                                              const float* c0T, float* hT)
{
    cg::grid_group grid = cg::this_grid();
    const int nt = blockIdx.x;
    const int b = threadIdx.x & 63;
    const int g16 = threadIdx.x >> 6;
    const int hcol = nt*16 + g16;                 // 0..303 (wave-uniform)
    float c = c0T[hcol*64 + b];
    const float4* wp = (const float4*)W4h_p + hcol;  // element [k][hcol], stride KH float4/row

    for (int t = 1; t < Tt; t++) {
        const float* hp = hT + (t-1)*Hh*64 + b;
        float ax = 0.0f, ay = 0.0f, az = 0.0f, aw = 0.0f;
#pragma unroll 4
        for (int k = 0; k < Hh; k++) {
            const float hv = hp[k*64];
            const float4 wv = wp[k*(N4P/4)];
            ax += hv*wv.x; ay += hv*wv.y; az += hv*wv.z; aw += hv*wv.w;
        }
        const float* gp = gpre + ((t-1)*N4P + 4*hcol)*64 + b;
        const float ig = sigmf_(ax + gp[0]);
        const float fg = sigmf_(ay + gp[64]);
        const float og = sigmf_(az + gp[128]);
        const float gg = tanhf (aw + gp[192]);
        c = fg*c + ig*gg;
        const float h = og*tanhf(c);
        if (hcol < Hh) hT[(t*Hh + hcol)*64 + b] = h;
        __threadfence();
        grid.sync();
    }
}

// ---------------------------------------------------------------------------
// tmp[t][j][b] = E[t][j][b] + (h_{t+1} @ Whp)[j][b] + pbias[j][b].
// grid (7 nt, 31 t), 192 thr, K=304.
// ---------------------------------------------------------------------------
__global__ __launch_bounds__(192) void k_gemm_tmp(const float* hT, const float* Whp,
                                                  const float* E, const float* ppb,
                                                  const float* pb_b, float* tmpT)
{
    const int nt = blockIdx.x, ti = blockIdx.y, tid = threadIdx.x;
    const int n0 = nt*48, tx = tid % 12, ty = tid / 12;
    __shared__ float As[16][64];
    __shared__ float Bs[16][48];
    float acc[4][4] = {};
    for (int kb = 0; kb < 19; kb++) {
        const int kbase = kb*16;
        for (int idx = tid; idx < 1024; idx += 192) {
            int kk = idx >> 6, bb = idx & 63, j = kbase + kk;
            As[kk][bb] = (j < Hh) ? hT[((ti+1)*Hh + j)*64 + bb] : 0.0f;
        }
        for (int idx = tid; idx < 768; idx += 192) {
            int kk = idx / 48, nn = idx % 48, j = kbase + kk, n = n0 + nn;
            Bs[kk][nn] = (j < Hh && n < Hh) ? Whp[j*Hh + n] : 0.0f;
        }
        __syncthreads();
#pragma unroll
        for (int kk = 0; kk < 16; kk++) {
            float4 av = *(const float4*)&As[kk][ty*4];
            float4 bv = *(const float4*)&Bs[kk][tx*4];
            fma16_(av, bv, acc);
        }
        __syncthreads();
    }
#pragma unroll
    for (int i = 0; i < 4; i++) {
        const int bb = ty*4 + i;
#pragma unroll
        for (int j = 0; j < 4; j++) {
            const int n = n0 + tx*4 + j;
            if (n < KOP) {
                float v = acc[i][j];
                if (n < Hh) {
                    float pb = pb_b[n];
                    for (int ks = 0; ks < 8; ks++) pb += ppb[(ks*NPP + n)*64 + bb];
                    v += E[(ti*Hh + n)*64 + bb] + pb;
                }
                tmpT[(ti*KOP + n)*64 + bb] = v;
            }
        }
    }
}

// Stage B: out[:, t+1, :] = tmp @ Wop + bop (raw). grid (7 ntiles, 31 t).
__global__ __launch_bounds__(192) void k_predb(const float* tmpT, const float* Wop,
                                               const float* bop, float* out)
{
    const int nt = blockIdx.x, ti = blockIdx.y, tid = threadIdx.x;
    const int n0 = nt*48, tx = tid % 12, ty = tid / 12;
    __shared__ float As[16][64];
    __shared__ float Bs[16][48];
    float acc[4][4] = {};
    const float* Asrc = tmpT + ti*KOP*64;

    for (int kb = 0; kb < 19; kb++) {
        const int kbase = kb*16;
        for (int idx = tid; idx < 1024; idx += 192) {
            int kk = idx >> 6, bb = idx & 63;
            As[kk][bb] = Asrc[(kbase + kk)*64 + bb];
        }
        for (int idx = tid; idx < 768; idx += 192) {
            int kk = idx / 48, nn = idx % 48, j = kbase + kk, n = n0 + nn;
            Bs[kk][nn] = (j < Hh && n < Hh) ? Wop[j*Hh + n] : 0.0f;
        }
        __syncthreads();
#pragma unroll
        for (int kk = 0; kk < 16; kk++) {
            float4 av = *(const float4*)&As[kk][ty*4];
            float4 bv = *(const float4*)&Bs[kk][tx*4];
            fma16_(av, bv, acc);
        }
        __syncthreads();
    }
#pragma unroll
    for (int i = 0; i < 4; i++) {
        const int bb = ty*4 + i;
#pragma unroll
        for (int j = 0; j < 4; j++) {
            const int n = n0 + tx*4 + j;
            if (n < Hh)
                out[(bb*Tt + (ti+1))*Hh + n] = acc[i][j] + bop[n];
        }
    }
}

// ---------------------------------------------------------------------------
extern "C" void kernel_launch(void* const* d_in, const int* in_sizes, int n_in,
                              void* d_out, int out_size, void* d_ws, size_t ws_size,
                              hipStream_t stream)
{
    const float* enc    = (const float*)d_in[0];
    const int*   caps   = (const int*)  d_in[1];
    const float* emb    = (const float*)d_in[2];
    const float* Wh0    = (const float*)d_in[3];
    const float* bh0    = (const float*)d_in[4];
    const float* Wc0    = (const float*)d_in[5];
    const float* bc0    = (const float*)d_in[6];
    const float* We_enc = (const float*)d_in[7];
    const float* We_hid = (const float*)d_in[8];
    const float* be     = (const float*)d_in[9];
    const float* Wi     = (const float*)d_in[10];
    const float* bi     = (const float*)d_in[11];
    const float* Wf     = (const float*)d_in[12];
    const float* bf     = (const float*)d_in[13];
    const float* Wo     = (const float*)d_in[14];
    const float* bo     = (const float*)d_in[15];
    const float* Wg     = (const float*)d_in[16];
    const float* bg     = (const float*)d_in[17];
    const float* Wcp    = (const float*)d_in[18];
    const float* bcp    = (const float*)d_in[19];
    const float* Whp    = (const float*)d_in[20];
    const float* bhp    = (const float*)d_in[21];
    const float* Wop    = (const float*)d_in[22];
    const float* bop    = (const float*)d_in[23];
    float* out = (float*)d_out;
    (void)We_hid; (void)be;   // softmax is invariant to the h-term: unused.

    // Workspace carve-up (floats).  Total ~5.56M floats (~22 MB).
    float* w = (float*)d_ws;
    float* W4h_p = w; w += KH*N4P;       //   369,664
    float* b4p   = w; w += N4P;
    float* pb_b  = w; w += NPP;
    float* bhc   = w; w += NH;
    float* e_enc = w; w += Bb*Cc;
    float* attnW = w; w += Bb*Cc;
    float* ctxT  = w; w += Ff*64;        //   131,072
    float* hT    = w; w += Tt*Hh*64;     //   614,400  h_t, t=0..31, [t][col][b]
    float* E     = w; w += 31*Hh*64;     //   595,200  emb_prev, [t][j][b]
    float* c0T   = w; w += KH*64;        //    19,456  [col][b]
    float* gpre  = w; w += 31*N4P*64;    // 2,412,544  [t][n][b]
    float* partC = w; w += 8*N4P*64;     //   622,592  [ks][n][b]
    float* ppb   = w; w += 8*NPP*64;     //   172,032  [ks][n][b]
    float* tmpT  = w; w += 31*KOP*64;    //   603,136  [t][j][b]
    // init-phase aliases (dead before tmpT is written by k_gemm_tmp)
    float* meanT = tmpT;                 // 131,072
    float* parth = tmpT + 131072;        // 319,488 (fits 603,136)
    (void)ws_size; (void)in_sizes; (void)n_in; (void)out_size;

    k_pack<<<512, 256, 0, stream>>>(Wi, Wf, Wo, Wg, bi, bf, bo, bg,
                                    bcp, bhp, bh0, bc0,
                                    W4h_p, b4p, pb_b, bhc);
    k_meanT<<<dim3(8, 64), 256, 0, stream>>>(enc, meanT);
    k_eenc <<<dim3(25, 64), 256, 0, stream>>>(enc, We_enc, e_enc);
    k_embed<<<2325, 256, 0, stream>>>(caps, emb, E);
    k_bos  <<<75, 256, 0, stream>>>(emb, out);
    k_attn <<<64, 64, 0, stream>>>(e_enc, attnW);
    k_ctx  <<<dim3(8, 64), 256, 0, stream>>>(enc, attnW, ctxT);
    k_gemm_h0<<<dim3(13, 8), 192, 0, stream>>>(meanT, Wh0, Wc0, parth);
    k_h0fin2<<<64, 256, 0, stream>>>(parth, bhc, hT, c0T);
    k_gemm_C<<<dim3(19, 8), 256, 0, stream>>>(ctxT, Wi, Wf, Wo, Wg, partC);
    k_gemm_gpre<<<dim3(19, 31), 256, 0, stream>>>(E, Wi, Wf, Wo, Wg, partC, b4p, gpre);
    k_gemm_pb<<<dim3(7, 8), 192, 0, stream>>>(ctxT, Wcp, ppb);

    {
        void* rargs[] = { (void*)&W4h_p, (void*)&gpre, (void*)&c0T, (void*)&hT };
        hipLaunchCooperativeKernel((const void*)k_rec, dim3(19), dim3(1024),
                                   rargs, 0, stream);
    }

    k_gemm_tmp<<<dim3(7, 31), 192, 0, stream>>>(hT, Whp, E, ppb, pb_b, tmpT);
    k_predb<<<dim3(7, 31), 192, 0, stream>>>(tmpT, Wop, bop, out);
}